// Round 6
// baseline (234.036 us; speedup 1.0000x reference)
//
#include <hip/hip_runtime.h>

// Problem constants (from reference)
#define CC 9605
#define BB 2048
#define LL 8
#define NEGF (-1e30f)
#define NINF (-__builtin_huge_valf())

// d_ws layout (unsigned words):
//   wsu[0] = wl entry count (atomic)
//   wsu[1] = dtype sniff flags (atomic OR)
//   wsu[4 .. 4+2048) = whitelist entries (col<<8 | mask)
//   byte offset 16384: float partials[BB]
#define WS_PARTIALS_OFF 16384

__device__ __forceinline__ unsigned enc_f(float f) {
  unsigned u = __float_as_uint(f);
  return (u & 0x80000000u) ? ~u : (u | 0x80000000u);
}
__device__ __forceinline__ float dec_u(unsigned e) {
  unsigned u = (e & 0x80000000u) ? (e & 0x7fffffffu) : ~e;
  return __uint_as_float(u);
}
__device__ __forceinline__ float sigm(float z) {
  return 1.0f / (1.0f + __expf(-z));
}

// ---- dtype sniff (word loads): byte signatures over the raw wl buffer ----
//   u8  : byte==1 at offsets %4 != 0        -> flag 1 (and 2)
//   i32 : byte==1 only at offsets %4 == 0   -> flag 2
//   f32 : 0x3f at %4==3, never byte==1      -> flag 8
//   bf16: 0x3f at odd offsets incl %4==1    -> flag 4 (and 8)
__global__ void wl_sniff(const unsigned* __restrict__ wlw,
                         unsigned* __restrict__ wsu) {
  const int nwords = (LL * CC) / 4;  // 76840 % 4 == 0
  const int stride = gridDim.x * blockDim.x;
  unsigned f = 0u;
  for (int j = blockIdx.x * blockDim.x + threadIdx.x; j < nwords; j += stride) {
    unsigned w = wlw[j];
#pragma unroll
    for (int k = 0; k < 4; ++k) {
      unsigned b = (w >> (8 * k)) & 255u;
      if (b == 1u)    { f |= 2u; if (k != 0) f |= 1u; }
      if (b == 0x3fu) { f |= 8u; if (k == 1) f |= 4u; }
    }
  }
#pragma unroll
  for (int off = 32; off >= 1; off >>= 1) f |= __shfl_xor(f, off, 64);
  if ((threadIdx.x & 63) == 0 && f) atomicOr(&wsu[1], f);
}

__global__ void wl_compact(const unsigned char* __restrict__ wl,
                           unsigned* __restrict__ wsu) {
  const int tid = threadIdx.x;
  const int lane = tid & 63;
  const int c = blockIdx.x * 256 + tid;
  const unsigned g = wsu[1];
  const int dt = (g & 1u) ? 0 : (g & 4u) ? 3 : (g & 2u) ? 1 : (g & 8u) ? 2 : 0;
  const int* wl32 = (const int*)wl;
  const float* wlf = (const float*)wl;
  const unsigned short* wlh = (const unsigned short*)wl;
  unsigned m = 0u;
  if (c < CC) {
#pragma unroll
    for (int l = 0; l < LL; ++l) {
      int j = l * CC + c;
      bool on;
      if (dt == 0) on = (wl[j] != 0);
      else if (dt == 1) on = (wl32[j] != 0);
      else if (dt == 2) on = (wlf[j] != 0.0f);
      else on = (wlh[j] != 0);
      if (on) m |= (1u << l);
    }
  }
  unsigned long long bal = __ballot(m != 0u);
  if (bal) {
    unsigned wcnt = (unsigned)__popcll(bal);
    unsigned basep = 0u;
    if (lane == 0) basep = atomicAdd(&wsu[0], wcnt);
    basep = __shfl(basep, 0, 64);
    if (m) {
      unsigned pos = basep + (unsigned)__popcll(bal & ((1ull << lane) - 1ull));
      if (pos < 2048u) wsu[4 + pos] = ((unsigned)c << 8) | m;
    }
  }
}

// ---------------------------------------------------------------------------
// ONE WAVE PER ROW. Rounds 0-5 proved the block-cooperative structure pays a
// ~13us/row-block critical path (5+ barriers x 8-wave rendezvous around a
// serial selection chain) that is insensitive to row residency, occupancy,
// shuffle count, and prefetching. This version deletes the structure: each
// 64-lane wave owns a full row; every lane keeps a sorted top-11 in 11 NAMED
// registers (branchless fmax/fmin bubble, 22 ops/value); the row-exact 11th
// largest comes from a wave binary search on the encoded value over the
// per-lane top-11s (counts via ballot bit-planes). No LDS. No barriers.
// ---------------------------------------------------------------------------

#define FOR11(OP) OP(0) OP(1) OP(2) OP(3) OP(4) OP(5) OP(6) OP(7) OP(8) OP(9) OP(10)
#define FOR8(OP) OP(0) OP(1) OP(2) OP(3) OP(4) OP(5) OP(6) OP(7)

#define DECL_S(k) float s_##k = NINF;
#define INS1(k) { float _hi = fmaxf(s_##k, cv); cv = fminf(s_##k, cv); s_##k = _hi; }
#define TOP11V(v) { float cv = (v); FOR11(INS1) }
#define TOP4(T) { TOP11V((T).x) TOP11V((T).y) TOP11V((T).z) TOP11V((T).w) }

__global__ __launch_bounds__(256) void loss_kernel(
    const float* __restrict__ x, const float* __restrict__ y,
    const unsigned* __restrict__ wsu, float* __restrict__ partials) {
  const int tid = threadIdx.x;
  const int lane = tid & 63;
  const int wid = tid >> 6;
  const int r = blockIdx.x * 4 + wid;          // one row per wave
  const long long base = (long long)r * CC;

  // ---- 0. whitelist gather slots: issue BEFORE the stream so the scattered
  //         loads complete under it. entv predicated (stale ws beyond nu).
  const unsigned nu = min(wsu[0], 2048u);
  const unsigned* ents = wsu + 4;
  unsigned entv[7];
  float gxv[7], gyv[7];
#pragma unroll
  for (int k = 0; k < 7; ++k) {
    unsigned e = (unsigned)lane + 64u * (unsigned)k;
    entv[k] = (e < nu) ? ents[e] : 0u;          // ents region always readable
  }
#pragma unroll
  for (int k = 0; k < 7; ++k) {
    int col = (int)(entv[k] >> 8);              // 0 for empty slot (safe addr)
    gxv[k] = x[base + col];
    gyv[k] = y[base + col];
  }

  // ---- 1. stream the row, maintaining per-lane sorted top-11 ----
  // Alignment: base % 4 == r % 4 (9605 % 4 == 1). Aligned float4 region
  // [soff, soff+4*ng); ng in {2400, 2401}; NF = ng>>6 == 37 always (CC fixed);
  // rem = ng - 2368 in {32, 33}; head+tail scalars m_extra <= 6.
  const int soff = (4 - (r & 3)) & 3;
  const int ng = (CC - soff) >> 2;
  const int rem = ng - 2368;
  const int tailn = CC - soff - (ng << 2);
  const int m_extra = soff + tailn;
  const float4* vp = (const float4*)(x + base + soff);

  FOR11(DECL_S)

  // 4-deep double-buffered pipeline: process a-batch while b-batch in flight.
  float4 a0 = vp[lane];
  float4 a1 = vp[lane + 64];
  float4 a2 = vp[lane + 128];
  float4 a3 = vp[lane + 192];
  int gb = lane;
  for (int i = 0; i + 8 <= 37; i += 4) {       // i = 0,4,...,28
    float4 b0 = vp[gb + 256];
    float4 b1 = vp[gb + 320];
    float4 b2 = vp[gb + 384];
    float4 b3 = vp[gb + 448];
    TOP4(a0) TOP4(a1) TOP4(a2) TOP4(a3)
    a0 = b0; a1 = b1; a2 = b2; a3 = b3;
    gb += 256;
  }
  // a holds groups 32..35
  TOP4(a0) TOP4(a1) TOP4(a2) TOP4(a3)
  {  // group 36 (all lanes: 36*64+63 = 2367 < 2400 <= ng)
    float4 t = vp[lane + 2304];
    TOP4(t)
  }
  {  // remainder groups 2368 .. ng-1 (lanes < rem)
    float4 t = make_float4(NINF, NINF, NINF, NINF);
    if (lane < rem) t = vp[2368 + lane];
    TOP4(t)
  }
  {  // scalar head [0,soff) + tail [soff+4ng, CC): <= 6 values
    float tv = NINF;
    if (lane < m_extra) {
      int tc = (lane < soff) ? lane : (soff + (ng << 2) + (lane - soff));
      tv = x[base + tc];
    }
    TOP11V(tv)
  }

  // ---- 2. encode the sorted top-11; wave window [lo, hi) ----
#define DECL_E(k) unsigned e_##k = enc_f(s_##k);
  FOR11(DECL_E)
  unsigned wlo = e_10;  // lane's 11th largest; wave-max is a valid lower bound
  unsigned whi = e_0;
#pragma unroll
  for (int off = 32; off >= 1; off >>= 1) {
    wlo = max(wlo, __shfl_xor(wlo, off, 64));
    whi = max(whi, __shfl_xor(whi, off, 64));
  }
  unsigned lo = wlo, hi = whi + 1u;
  // Row values outside a lane's top-11 are < that lane's e_10 <= lo, so
  // counting candidates only is exact for any threshold >= lo.
  while (hi - lo > 1u) {                       // uniform; <= ~25 iters
    unsigned mid = lo + ((hi - lo) >> 1);
    unsigned cnt = 0u;
#define CMP1(k) cnt += (e_##k >= mid) ? 1u : 0u;
    FOR11(CMP1)
#undef CMP1
    unsigned tot = (unsigned)__popcll(__ballot(cnt & 1u)) +
                   ((unsigned)__popcll(__ballot(cnt & 2u)) << 1) +
                   ((unsigned)__popcll(__ballot(cnt & 4u)) << 2) +
                   ((unsigned)__popcll(__ballot(cnt & 8u)) << 3);
    if (tot >= 11u) lo = mid; else hi = mid;
  }
  const unsigned E11 = lo;  // exact 11th-largest (encoded); ties handled

  // ---- 3. whitelist fold (gathers from step 0 long arrived) ----
#define DECL_LM(k) float lm_##k = NEGF;
  FOR8(DECL_LM)
  unsigned pmask = 0u;  // bits0-7: label present; bits8-15: label has positive
#pragma unroll
  for (int k = 0; k < 7; ++k) {
    unsigned mk = entv[k] & 255u;               // 0 for empty slot -> no-op
    pmask |= mk;
    if (gyv[k] > 0.0f) pmask |= (mk << 8);
#define FOLD1(l) if ((mk >> l) & 1u) lm_##l = fmaxf(lm_##l, gxv[k]);
    FOR8(FOLD1)
#undef FOLD1
  }
  // safety net (nu <= ~400 in this problem; loop normally never runs)
  for (unsigned e = (unsigned)lane + 448u; e < nu; e += 64u) {
    unsigned ent = ents[e];
    unsigned mk = ent & 255u;
    float xv = x[base + (ent >> 8)];
    float yv = y[base + (ent >> 8)];
    pmask |= mk;
    if (yv > 0.0f) pmask |= (mk << 8);
#define FOLD1(l) if ((mk >> l) & 1u) lm_##l = fmaxf(lm_##l, xv);
    FOR8(FOLD1)
#undef FOLD1
  }
#pragma unroll
  for (int off = 32; off >= 1; off >>= 1) {
    pmask |= __shfl_xor(pmask, off, 64);
#define RED1(l) lm_##l = fmaxf(lm_##l, __shfl_xor(lm_##l, off, 64));
    FOR8(RED1)
#undef RED1
  }

  // ---- 4. lane 0: per-row loss ----
  if (lane == 0) {
    unsigned PR = pmask & 255u, PO = (pmask >> 8) & 255u;
    float thres = fmaxf(sigm(dec_u(E11)), 0.5f);
    float cmax = NEGF, imax = NEGF, umax = NEGF;
#define EP1(l)                                                   \
    if ((PR >> l) & 1u) {                                        \
      float ml = sigm(lm_##l);                                   \
      umax = fmaxf(umax, ml);                                    \
      if ((PO >> l) & 1u) cmax = fmaxf(cmax, ml);                \
      else imax = fmaxf(imax, ml);                               \
    }
    FOR8(EP1)
#undef EP1
    bool anyc = (PO != 0u);
    bool anyi = (PO != 255u);  // L == 8 labels always exist
    float x1 = anyc ? cmax : thres;
    float x2 = anyc ? (anyi ? fmaxf(imax, thres) : thres)
                    : ((nu > 0u) ? umax : NEGF);
    float coef = anyc ? 1.0f : 0.5f;
    float dd = x2 - x1 + 0.1f;
    float rank = ((dd > 0.0f) ? 2.0f : 1.0f) * sigm(10.0f * dd);
    partials[r] = coef * rank;
  }
}

__global__ void final_reduce(const float* __restrict__ partials,
                             float* __restrict__ out) {
  __shared__ float sh[4];
  const int tid = threadIdx.x;
  const int lane = tid & 63;
  const int wid = tid >> 6;
  float s = 0.0f;
  for (int i = tid; i < BB; i += 256) s += partials[i];
#pragma unroll
  for (int off = 32; off >= 1; off >>= 1) s += __shfl_xor(s, off, 64);
  if (lane == 0) sh[wid] = s;
  __syncthreads();
  if (tid == 0) out[0] = (sh[0] + sh[1] + sh[2] + sh[3]) * (1.0f / (float)BB);
}

extern "C" void kernel_launch(void* const* d_in, const int* in_sizes, int n_in,
                              void* d_out, int out_size, void* d_ws,
                              size_t ws_size, hipStream_t stream) {
  const float* x = (const float*)d_in[0];
  const float* y = (const float*)d_in[1];
  // d_in[2] (y_neg) is faithfully ignored — it never affects the loss.
  const unsigned char* wl = (const unsigned char*)d_in[3];
  float* out = (float*)d_out;
  unsigned* wsu = (unsigned*)d_ws;
  float* partials = (float*)((char*)d_ws + WS_PARTIALS_OFF);

  hipMemsetAsync(d_ws, 0, 16, stream);  // zero wsu[0..3]
  wl_sniff<<<64, 256, 0, stream>>>((const unsigned*)wl, wsu);
  wl_compact<<<(CC + 255) / 256, 256, 0, stream>>>(wl, wsu);
  loss_kernel<<<BB / 4, 256, 0, stream>>>(x, y, wsu, partials);
  final_reduce<<<1, 256, 0, stream>>>(partials, out);
}

// Round 8
// 222.897 us; speedup vs baseline: 1.0500x; 1.0500x over previous
//
#include <hip/hip_runtime.h>

// Problem constants (from reference)
#define CC 9605
#define BB 2048
#define LL 8
#define NEGF (-1e30f)
#define NINF (-__builtin_huge_valf())

// d_ws layout (unsigned words):
//   wsu[0] = wl entry count (atomic)
//   wsu[1] = dtype sniff flags (atomic OR)
//   wsu[4 .. 4+2048) = whitelist entries (col<<8 | mask)
//   byte offset 16384: float partials[BB]
#define WS_PARTIALS_OFF 16384

__device__ __forceinline__ unsigned enc_f(float f) {
  unsigned u = __float_as_uint(f);
  return (u & 0x80000000u) ? ~u : (u | 0x80000000u);
}
__device__ __forceinline__ float dec_u(unsigned e) {
  unsigned u = (e & 0x80000000u) ? (e & 0x7fffffffu) : ~e;
  return __uint_as_float(u);
}
__device__ __forceinline__ float sigm(float z) {
  return 1.0f / (1.0f + __expf(-z));
}

// ---- dtype sniff (word loads): byte signatures over the raw wl buffer ----
//   u8  : byte==1 at offsets %4 != 0        -> flag 1 (and 2)
//   i32 : byte==1 only at offsets %4 == 0   -> flag 2
//   f32 : 0x3f at %4==3, never byte==1      -> flag 8
//   bf16: 0x3f at odd offsets incl %4==1    -> flag 4 (and 8)
__global__ void wl_sniff(const unsigned* __restrict__ wlw,
                         unsigned* __restrict__ wsu) {
  const int nwords = (LL * CC) / 4;  // 76840 % 4 == 0
  const int stride = gridDim.x * blockDim.x;
  unsigned f = 0u;
  for (int j = blockIdx.x * blockDim.x + threadIdx.x; j < nwords; j += stride) {
    unsigned w = wlw[j];
#pragma unroll
    for (int k = 0; k < 4; ++k) {
      unsigned b = (w >> (8 * k)) & 255u;
      if (b == 1u)    { f |= 2u; if (k != 0) f |= 1u; }
      if (b == 0x3fu) { f |= 8u; if (k == 1) f |= 4u; }
    }
  }
#pragma unroll
  for (int off = 32; off >= 1; off >>= 1) f |= __shfl_xor(f, off, 64);
  if ((threadIdx.x & 63) == 0 && f) atomicOr(&wsu[1], f);
}

__global__ void wl_compact(const unsigned char* __restrict__ wl,
                           unsigned* __restrict__ wsu) {
  const int tid = threadIdx.x;
  const int lane = tid & 63;
  const int c = blockIdx.x * 256 + tid;
  const unsigned g = wsu[1];
  const int dt = (g & 1u) ? 0 : (g & 4u) ? 3 : (g & 2u) ? 1 : (g & 8u) ? 2 : 0;
  const int* wl32 = (const int*)wl;
  const float* wlf = (const float*)wl;
  const unsigned short* wlh = (const unsigned short*)wl;
  unsigned m = 0u;
  if (c < CC) {
#pragma unroll
    for (int l = 0; l < LL; ++l) {
      int j = l * CC + c;
      bool on;
      if (dt == 0) on = (wl[j] != 0);
      else if (dt == 1) on = (wl32[j] != 0);
      else if (dt == 2) on = (wlf[j] != 0.0f);
      else on = (wlh[j] != 0);
      if (on) m |= (1u << l);
    }
  }
  unsigned long long bal = __ballot(m != 0u);
  if (bal) {
    unsigned wcnt = (unsigned)__popcll(bal);
    unsigned basep = 0u;
    if (lane == 0) basep = atomicAdd(&wsu[0], wcnt);
    basep = __shfl(basep, 0, 64);
    if (m) {
      unsigned pos = basep + (unsigned)__popcll(bal & ((1ull << lane) - 1ull));
      if (pos < 2048u) wsu[4 + pos] = ((unsigned)c << 8) | m;
    }
  }
}

// ---------------------------------------------------------------------------
// TWO WAVES PER ROW, SPILL-PROOF (R7 design; R7 failed only on a macro
// recursion: FOR11(MG1) -> TOP11V -> FOR11(INS1) never expands because a
// macro is "blue-painted" inside its own expansion. Fix: TOP11V iterates via
// a separately named FOR11I.)
//   (1) __launch_bounds__(128, 1): min-1-wave/EU -> 512-VGPR budget, the
//       compiler cannot spill the hot top-11 state (R6: VGPR=36 => the
//       22-op insert chain ran through scratch, 150x per lane ~= 72us).
//   (2) 2 waves/row: halves the per-wave serial chain, doubles TLP to
//       16 waves/CU. One LDS merge (2.9KB) + ONE barrier per row.
//   (3) whitelist gathers AFTER the stream: x-gathers hit L2/L3 (row just
//       streamed; x fits in 256MB L3) -> kills R6's +24MB double-fetch.
// ---------------------------------------------------------------------------

#define FOR11(OP) OP(0) OP(1) OP(2) OP(3) OP(4) OP(5) OP(6) OP(7) OP(8) OP(9) OP(10)
#define FOR11I(OP) OP(0) OP(1) OP(2) OP(3) OP(4) OP(5) OP(6) OP(7) OP(8) OP(9) OP(10)
#define FOR8(OP) OP(0) OP(1) OP(2) OP(3) OP(4) OP(5) OP(6) OP(7)

#define DECL_S(k) float s_##k = NINF;
#define INS1(k) { float _hi = fmaxf(s_##k, cv); cv = fminf(s_##k, cv); s_##k = _hi; }
#define TOP11V(v) { float cv = (v); FOR11I(INS1) }
#define TOP4(T) { TOP11V((T).x) TOP11V((T).y) TOP11V((T).z) TOP11V((T).w) }

__global__ __launch_bounds__(128, 1) void loss_kernel(
    const float* __restrict__ x, const float* __restrict__ y,
    const unsigned* __restrict__ wsu, float* __restrict__ partials) {
  __shared__ float sh_top[64][11];   // wave1 per-lane top-11 (float)
  __shared__ float sh_w1lm[8];       // wave1 reduced whitelist maxes
  __shared__ unsigned sh_w1pm;       // wave1 reduced pmask

  const int tid = threadIdx.x;
  const int lane = tid & 63;
  const int w = tid >> 6;            // 0 or 1
  const int r = blockIdx.x;          // one row per block
  const long long base = (long long)r * CC;

  const unsigned nu = min(wsu[0], 2048u);
  const unsigned* ents = wsu + 4;

  // Alignment: aligned float4 region [soff, soff+4*ng); ng in {2400,2401};
  // head+tail scalars m_extra <= 6. Split: wave0 groups [0,1216) (19/lane),
  // wave1 groups [1216,2368) (18/lane) + rem [2368,ng) + scalars.
  const int soff = (4 - (r & 3)) & 3;
  const int ng = (CC - soff) >> 2;
  const int rem = ng - 2368;                    // 32 or 33
  const int tailn = CC - soff - (ng << 2);
  const int m_extra = soff + tailn;
  const float4* vp = (const float4*)(x + base + soff);

  FOR11(DECL_S)

  // ---- 1. stream this wave's half, 4-group double-buffered ----
  const int g0 = w ? 1216 : 0;
  float4 a0 = vp[g0 + lane];
  float4 a1 = vp[g0 + lane + 64];
  float4 a2 = vp[g0 + lane + 128];
  float4 a3 = vp[g0 + lane + 192];
  int gb = g0 + lane;
#pragma unroll 1
  for (int it = 0; it < 3; ++it) {   // process j0-11, prefetch j4-15
    float4 b0 = vp[gb + 256];
    float4 b1 = vp[gb + 320];
    float4 b2 = vp[gb + 384];
    float4 b3 = vp[gb + 448];
    TOP4(a0) TOP4(a1) TOP4(a2) TOP4(a3)
    a0 = b0; a1 = b1; a2 = b2; a3 = b3;
    gb += 256;
  }
  // a holds groups j12..j15 of this wave's half
  if (w == 0) {
    float4 b0 = vp[gb + 256];        // j16
    float4 b1 = vp[gb + 320];        // j17
    float4 b2 = vp[gb + 384];        // j18 (last: 1152+63 = 1215 < 1216)
    TOP4(a0) TOP4(a1) TOP4(a2) TOP4(a3)
    TOP4(b0) TOP4(b1) TOP4(b2)
  } else {
    float4 b0 = vp[gb + 256];        // j16
    float4 b1 = vp[gb + 320];        // j17 (last full: 2304+63 = 2367)
    float4 tr = make_float4(NINF, NINF, NINF, NINF);
    if (lane < rem) tr = vp[2368 + lane];
    float tv = NINF;
    if (lane < m_extra) {
      int tc = (lane < soff) ? lane : (soff + (ng << 2) + (lane - soff));
      tv = x[base + tc];
    }
    TOP4(a0) TOP4(a1) TOP4(a2) TOP4(a3)
    TOP4(b0) TOP4(b1) TOP4(tr)
    TOP11V(tv)
  }

  // ---- 2. whitelist gathers (AFTER stream: x-gathers are L2/L3 hits) ----
  // entry partition: wave w takes e = lane + 64*(2k+w), k=0..3 (covers <512)
  unsigned en0, en1, en2, en3;
  {
    unsigned e0 = (unsigned)lane + 64u * (unsigned)w;
    en0 = (e0 < nu) ? ents[e0] : 0u;
    en1 = (e0 + 128u < nu) ? ents[e0 + 128u] : 0u;
    en2 = (e0 + 256u < nu) ? ents[e0 + 256u] : 0u;
    en3 = (e0 + 384u < nu) ? ents[e0 + 384u] : 0u;
  }
  float gx0 = x[base + (en0 >> 8)], gy0 = y[base + (en0 >> 8)];
  float gx1 = x[base + (en1 >> 8)], gy1 = y[base + (en1 >> 8)];
  float gx2 = x[base + (en2 >> 8)], gy2 = y[base + (en2 >> 8)];
  float gx3 = x[base + (en3 >> 8)], gy3 = y[base + (en3 >> 8)];

#define DECL_LM(k) float lm_##k = NEGF;
  FOR8(DECL_LM)
  unsigned pmask = 0u;  // bits0-7: label present; bits8-15: label has positive
#define FOLDE(EN, GX, GY)                                        \
  {                                                              \
    unsigned mk = (EN) & 255u; /* 0 for empty slot -> no-op */   \
    pmask |= mk;                                                 \
    if ((GY) > 0.0f) pmask |= (mk << 8);                         \
    if (mk & 1u)   lm_0 = fmaxf(lm_0, (GX));                     \
    if (mk & 2u)   lm_1 = fmaxf(lm_1, (GX));                     \
    if (mk & 4u)   lm_2 = fmaxf(lm_2, (GX));                     \
    if (mk & 8u)   lm_3 = fmaxf(lm_3, (GX));                     \
    if (mk & 16u)  lm_4 = fmaxf(lm_4, (GX));                     \
    if (mk & 32u)  lm_5 = fmaxf(lm_5, (GX));                     \
    if (mk & 64u)  lm_6 = fmaxf(lm_6, (GX));                     \
    if (mk & 128u) lm_7 = fmaxf(lm_7, (GX));                     \
  }
  FOLDE(en0, gx0, gy0)
  FOLDE(en1, gx1, gy1)
  FOLDE(en2, gx2, gy2)
  FOLDE(en3, gx3, gy3)
  // safety net (nu <= ~400 here; loop normally never runs); each entry
  // handled exactly once per block: e = 512 + tid, step 128
  for (unsigned e = 512u + (unsigned)tid; e < nu; e += 128u) {
    unsigned ent = ents[e];
    float xv = x[base + (ent >> 8)];
    float yv = y[base + (ent >> 8)];
    FOLDE(ent, xv, yv)
  }
#pragma unroll
  for (int off = 32; off >= 1; off >>= 1) {
    pmask |= __shfl_xor(pmask, off, 64);
#define RED1(l) lm_##l = fmaxf(lm_##l, __shfl_xor(lm_##l, off, 64));
    FOR8(RED1)
#undef RED1
  }

  // ---- 3. wave1 publishes; ONE barrier; wave0 merges ----
  if (w == 1) {
#define ST1(k) sh_top[lane][k] = s_##k;
    FOR11(ST1)
#undef ST1
    if (lane == 0) {
#define STL(l) sh_w1lm[l] = lm_##l;
      FOR8(STL)
#undef STL
      sh_w1pm = pmask;
    }
  }
  __syncthreads();
  if (w != 0) return;

  // merge wave1's lane top-11 into ours (row top-11 preserved: any value
  // dropped anywhere is exceeded by 11 values in that lane's multiset)
#define MG1(k) TOP11V(sh_top[lane][k])
  FOR11(MG1)
#undef MG1

  // ---- 4. exact 11th-largest via value binary search (ballots only) ----
#define DECL_E(k) unsigned e_##k = enc_f(s_##k);
  FOR11(DECL_E)
#undef DECL_E
  unsigned wlo = e_10;  // lane's 11th; wave-max is a valid lower bound
  unsigned whi = e_0;
#pragma unroll
  for (int off = 32; off >= 1; off >>= 1) {
    wlo = max(wlo, __shfl_xor(wlo, off, 64));
    whi = max(whi, __shfl_xor(whi, off, 64));
  }
  unsigned lo = wlo, hi = whi + 1u;
  // Values dropped from any lane's merged top-11 are < that lane's e_10
  // <= lo, so candidate counts are exact for any threshold > lo.
  while (hi - lo > 1u) {             // uniform; <= ~25 iters
    unsigned mid = lo + ((hi - lo) >> 1);
    unsigned cnt = 0u;
#define CMP1(k) cnt += (e_##k >= mid) ? 1u : 0u;
    FOR11(CMP1)
#undef CMP1
    unsigned tot = (unsigned)__popcll(__ballot(cnt & 1u)) +
                   ((unsigned)__popcll(__ballot(cnt & 2u)) << 1) +
                   ((unsigned)__popcll(__ballot(cnt & 4u)) << 2) +
                   ((unsigned)__popcll(__ballot(cnt & 8u)) << 3);
    if (tot >= 11u) lo = mid; else hi = mid;
  }
  const unsigned E11 = lo;  // exact 11th-largest (encoded)

  // ---- 5. lane 0: combine with wave1 partials, per-row loss ----
  if (lane == 0) {
    pmask |= sh_w1pm;
#define CMB(l) lm_##l = fmaxf(lm_##l, sh_w1lm[l]);
    FOR8(CMB)
#undef CMB
    unsigned PR = pmask & 255u, PO = (pmask >> 8) & 255u;
    float thres = fmaxf(sigm(dec_u(E11)), 0.5f);
    float cmax = NEGF, imax = NEGF, umax = NEGF;
#define EP1(l)                                                   \
    if ((PR >> l) & 1u) {                                        \
      float ml = sigm(lm_##l);                                   \
      umax = fmaxf(umax, ml);                                    \
      if ((PO >> l) & 1u) cmax = fmaxf(cmax, ml);                \
      else imax = fmaxf(imax, ml);                               \
    }
    FOR8(EP1)
#undef EP1
    bool anyc = (PO != 0u);
    bool anyi = (PO != 255u);  // L == 8 labels always exist
    float x1 = anyc ? cmax : thres;
    float x2 = anyc ? (anyi ? fmaxf(imax, thres) : thres)
                    : ((nu > 0u) ? umax : NEGF);
    float coef = anyc ? 1.0f : 0.5f;
    float dd = x2 - x1 + 0.1f;
    float rank = ((dd > 0.0f) ? 2.0f : 1.0f) * sigm(10.0f * dd);
    partials[r] = coef * rank;
  }
}

__global__ void final_reduce(const float* __restrict__ partials,
                             float* __restrict__ out) {
  __shared__ float sh[4];
  const int tid = threadIdx.x;
  const int lane = tid & 63;
  const int wid = tid >> 6;
  float s = 0.0f;
  for (int i = tid; i < BB; i += 256) s += partials[i];
#pragma unroll
  for (int off = 32; off >= 1; off >>= 1) s += __shfl_xor(s, off, 64);
  if (lane == 0) sh[wid] = s;
  __syncthreads();
  if (tid == 0) out[0] = (sh[0] + sh[1] + sh[2] + sh[3]) * (1.0f / (float)BB);
}

extern "C" void kernel_launch(void* const* d_in, const int* in_sizes, int n_in,
                              void* d_out, int out_size, void* d_ws,
                              size_t ws_size, hipStream_t stream) {
  const float* x = (const float*)d_in[0];
  const float* y = (const float*)d_in[1];
  // d_in[2] (y_neg) is faithfully ignored — it never affects the loss.
  const unsigned char* wl = (const unsigned char*)d_in[3];
  float* out = (float*)d_out;
  unsigned* wsu = (unsigned*)d_ws;
  float* partials = (float*)((char*)d_ws + WS_PARTIALS_OFF);

  hipMemsetAsync(d_ws, 0, 16, stream);  // zero wsu[0..3]
  wl_sniff<<<64, 256, 0, stream>>>((const unsigned*)wl, wsu);
  wl_compact<<<(CC + 255) / 256, 256, 0, stream>>>(wl, wsu);
  loss_kernel<<<BB, 128, 0, stream>>>(x, y, wsu, partials);
  final_reduce<<<1, 256, 0, stream>>>(partials, out);
}

// Round 9
// 222.152 us; speedup vs baseline: 1.0535x; 1.0034x over previous
//
#include <hip/hip_runtime.h>

// Problem constants (from reference)
#define CC 9605
#define BB 2048
#define LL 8
#define NEGF (-1e30f)
#define NINF (-__builtin_huge_valf())

// d_ws layout (unsigned words):
//   wsu[0] = wl entry count (atomic)
//   wsu[1] = dtype sniff flags (atomic OR)
//   wsu[4 .. 4+2048) = whitelist entries (col<<8 | mask)
//   byte offset 16384: float partials[BB]
#define WS_PARTIALS_OFF 16384

__device__ __forceinline__ unsigned enc_f(float f) {
  unsigned u = __float_as_uint(f);
  return (u & 0x80000000u) ? ~u : (u | 0x80000000u);
}
__device__ __forceinline__ float dec_u(unsigned e) {
  unsigned u = (e & 0x80000000u) ? (e & 0x7fffffffu) : ~e;
  return __uint_as_float(u);
}
__device__ __forceinline__ float sigm(float z) {
  return 1.0f / (1.0f + __expf(-z));
}

// ---- dtype sniff (word loads): byte signatures over the raw wl buffer ----
//   u8  : byte==1 at offsets %4 != 0        -> flag 1 (and 2)
//   i32 : byte==1 only at offsets %4 == 0   -> flag 2
//   f32 : 0x3f at %4==3, never byte==1      -> flag 8
//   bf16: 0x3f at odd offsets incl %4==1    -> flag 4 (and 8)
__global__ void wl_sniff(const unsigned* __restrict__ wlw,
                         unsigned* __restrict__ wsu) {
  const int nwords = (LL * CC) / 4;  // 76840 % 4 == 0
  const int stride = gridDim.x * blockDim.x;
  unsigned f = 0u;
  for (int j = blockIdx.x * blockDim.x + threadIdx.x; j < nwords; j += stride) {
    unsigned w = wlw[j];
#pragma unroll
    for (int k = 0; k < 4; ++k) {
      unsigned b = (w >> (8 * k)) & 255u;
      if (b == 1u)    { f |= 2u; if (k != 0) f |= 1u; }
      if (b == 0x3fu) { f |= 8u; if (k == 1) f |= 4u; }
    }
  }
#pragma unroll
  for (int off = 32; off >= 1; off >>= 1) f |= __shfl_xor(f, off, 64);
  if ((threadIdx.x & 63) == 0 && f) atomicOr(&wsu[1], f);
}

__global__ void wl_compact(const unsigned char* __restrict__ wl,
                           unsigned* __restrict__ wsu) {
  const int tid = threadIdx.x;
  const int lane = tid & 63;
  const int c = blockIdx.x * 256 + tid;
  const unsigned g = wsu[1];
  const int dt = (g & 1u) ? 0 : (g & 4u) ? 3 : (g & 2u) ? 1 : (g & 8u) ? 2 : 0;
  const int* wl32 = (const int*)wl;
  const float* wlf = (const float*)wl;
  const unsigned short* wlh = (const unsigned short*)wl;
  unsigned m = 0u;
  if (c < CC) {
#pragma unroll
    for (int l = 0; l < LL; ++l) {
      int j = l * CC + c;
      bool on;
      if (dt == 0) on = (wl[j] != 0);
      else if (dt == 1) on = (wl32[j] != 0);
      else if (dt == 2) on = (wlf[j] != 0.0f);
      else on = (wlh[j] != 0);
      if (on) m |= (1u << l);
    }
  }
  unsigned long long bal = __ballot(m != 0u);
  if (bal) {
    unsigned wcnt = (unsigned)__popcll(bal);
    unsigned basep = 0u;
    if (lane == 0) basep = atomicAdd(&wsu[0], wcnt);
    basep = __shfl(basep, 0, 64);
    if (m) {
      unsigned pos = basep + (unsigned)__popcll(bal & ((1ull << lane) - 1ull));
      if (pos < 2048u) wsu[4 + pos] = ((unsigned)c << 8) | m;
    }
  }
}

// ---------------------------------------------------------------------------
// FOUR WAVES PER ROW, FULL OCCUPANCY. R8's counters (VGPR=28, WRITE=65KB:
// no spill!) revealed the real compiler behavior: hipcc minimizes register
// pressure regardless of launch_bounds, sinking prefetch loads to their use
// -> every source-level pipeline this session was collapsed to serialized
// load->wait->compute (~40% duty/wave). So hide latency with TLP, not ILP:
// 256-thread blocks x 2048 = 8192 waves = 100% of device wave slots
// (8 blocks/CU; ~40 VGPR, 8.6KB LDS both fit 8 blocks). Each wave streams
// 600 float4-groups (~37 values/lane) into a named-register sorted top-11;
// waves 1-3 publish 11 floats/lane to LDS (stride 11 words -> conflict-
// free); ONE barrier; wave0 merges 33 inserts/lane and binary-searches the
// exact 11th-largest by value (ballot counts only).
// Exactness: any dropped value < its lane's stream-11th <= that lane's
// merged-11th <= lo = wave-max(merged 11th) (11 values >= stream-11th exist
// in the fed set), so counts over merged lists are exact for T > lo.
// ---------------------------------------------------------------------------

#define FOR11(OP) OP(0) OP(1) OP(2) OP(3) OP(4) OP(5) OP(6) OP(7) OP(8) OP(9) OP(10)
#define FOR11I(OP) OP(0) OP(1) OP(2) OP(3) OP(4) OP(5) OP(6) OP(7) OP(8) OP(9) OP(10)
#define FOR8(OP) OP(0) OP(1) OP(2) OP(3) OP(4) OP(5) OP(6) OP(7)

#define DECL_S(k) float s_##k = NINF;
#define INS1(k) { float _hi = fmaxf(s_##k, cv); cv = fminf(s_##k, cv); s_##k = _hi; }
#define TOP11V(v) { float cv = (v); FOR11I(INS1) }
#define TOP4(T) { TOP11V((T).x) TOP11V((T).y) TOP11V((T).z) TOP11V((T).w) }

__global__ __launch_bounds__(256) void loss_kernel(
    const float* __restrict__ x, const float* __restrict__ y,
    const unsigned* __restrict__ wsu, float* __restrict__ partials) {
  __shared__ float sh_top[3][64][11];  // waves 1-3 per-lane top-11
  __shared__ float sh_wlm[4][8];       // per-wave reduced whitelist maxes
  __shared__ unsigned sh_wpm[4];       // per-wave reduced pmask

  const int tid = threadIdx.x;
  const int lane = tid & 63;
  const int w = tid >> 6;              // 0..3
  const int r = blockIdx.x;            // one row per block
  const long long base = (long long)r * CC;

  const unsigned nu = min(wsu[0], 2048u);
  const unsigned* ents = wsu + 4;

  // Aligned float4 region [soff, soff+4*ng); ng in {2400,2401}; head+tail
  // scalars m_extra <= 5. Wave w streams groups [600w, 600w+600); the 600 =
  // 9 full 64-lane rounds + 24-lane round. Wave 3 additionally takes group
  // 2400 (when ng==2401) and the scalars.
  const int soff = (4 - (r & 3)) & 3;
  const int ng = (CC - soff) >> 2;
  const int tailn = CC - soff - (ng << 2);
  const int m_extra = soff + tailn;
  const float4* vp = (const float4*)(x + base + soff);

  FOR11(DECL_S)

  // ---- 1. stream this wave's 600 groups ----
  const int g0 = 600 * w + lane;
#pragma unroll
  for (int k = 0; k < 9; ++k) {        // 600w + lane + 64k <= 600w+575
    float4 t = vp[g0 + 64 * k];
    TOP4(t)
  }
  {                                     // groups 600w+576 .. 600w+599
    float4 t = make_float4(NINF, NINF, NINF, NINF);
    if (lane < 24) t = vp[600 * w + 576 + lane];
    TOP4(t)
  }
  if (w == 3) {
    {                                   // group 2400 iff ng == 2401
      float4 t = make_float4(NINF, NINF, NINF, NINF);
      if (2400 + lane < ng) t = vp[2400 + lane];
      TOP4(t)
    }
    float tv = NINF;                    // scalar head + tail (<= 5 values)
    if (lane < m_extra) {
      int tc = (lane < soff) ? lane : (soff + (ng << 2) + (lane - soff));
      tv = x[base + tc];
    }
    TOP11V(tv)
  }

  // ---- 2. whitelist gathers (after stream: x-gathers hit L1/L2) ----
  unsigned en0 = ((unsigned)tid < nu) ? ents[tid] : 0u;
  unsigned en1 = ((unsigned)tid + 256u < nu) ? ents[tid + 256] : 0u;
  float gx0 = x[base + (en0 >> 8)], gy0 = y[base + (en0 >> 8)];
  float gx1 = x[base + (en1 >> 8)], gy1 = y[base + (en1 >> 8)];

#define DECL_LM(k) float lm_##k = NEGF;
  FOR8(DECL_LM)
  unsigned pmask = 0u;  // bits0-7: label present; bits8-15: label has positive
#define FOLDE(EN, GX, GY)                                        \
  {                                                              \
    unsigned mk = (EN) & 255u; /* 0 for empty slot -> no-op */   \
    pmask |= mk;                                                 \
    if ((GY) > 0.0f) pmask |= (mk << 8);                         \
    if (mk & 1u)   lm_0 = fmaxf(lm_0, (GX));                     \
    if (mk & 2u)   lm_1 = fmaxf(lm_1, (GX));                     \
    if (mk & 4u)   lm_2 = fmaxf(lm_2, (GX));                     \
    if (mk & 8u)   lm_3 = fmaxf(lm_3, (GX));                     \
    if (mk & 16u)  lm_4 = fmaxf(lm_4, (GX));                     \
    if (mk & 32u)  lm_5 = fmaxf(lm_5, (GX));                     \
    if (mk & 64u)  lm_6 = fmaxf(lm_6, (GX));                     \
    if (mk & 128u) lm_7 = fmaxf(lm_7, (GX));                     \
  }
  FOLDE(en0, gx0, gy0)
  FOLDE(en1, gx1, gy1)
  // safety net (nu <= ~400 here; loop normally never runs)
  for (unsigned e = 512u + (unsigned)tid; e < nu; e += 256u) {
    unsigned ent = ents[e];
    float xv = x[base + (ent >> 8)];
    float yv = y[base + (ent >> 8)];
    FOLDE(ent, xv, yv)
  }
#pragma unroll
  for (int off = 32; off >= 1; off >>= 1) {
    pmask |= __shfl_xor(pmask, off, 64);
#define RED1(l) lm_##l = fmaxf(lm_##l, __shfl_xor(lm_##l, off, 64));
    FOR8(RED1)
#undef RED1
  }

  // ---- 3. waves 1-3 publish; ONE barrier; wave0 merges ----
  if (w > 0) {
#define ST1(k) sh_top[w - 1][lane][k] = s_##k;
    FOR11(ST1)
#undef ST1
  }
  if (lane == 0) {
#define STL(l) sh_wlm[w][l] = lm_##l;
    FOR8(STL)
#undef STL
    sh_wpm[w] = pmask;
  }
  __syncthreads();
  if (w != 0) return;

  // merge waves 1-3 per-lane lists (33 inserts; LDS stride 11 words ->
  // lanes spread across all 32 banks, conflict-free)
#pragma unroll
  for (int j = 0; j < 3; ++j) {
#pragma unroll
    for (int k = 0; k < 11; ++k) {
      TOP11V(sh_top[j][lane][k])
    }
  }

  // ---- 4. exact 11th-largest via value binary search (ballots only) ----
#define DECL_E(k) unsigned e_##k = enc_f(s_##k);
  FOR11(DECL_E)
#undef DECL_E
  unsigned wlo = e_10;  // lane's merged 11th; wave-max is a valid lower bound
  unsigned whi = e_0;
#pragma unroll
  for (int off = 32; off >= 1; off >>= 1) {
    wlo = max(wlo, __shfl_xor(wlo, off, 64));
    whi = max(whi, __shfl_xor(whi, off, 64));
  }
  unsigned lo = wlo, hi = whi + 1u;
  while (hi - lo > 1u) {               // uniform; <= ~25 iters
    unsigned mid = lo + ((hi - lo) >> 1);
    unsigned cnt = 0u;
#define CMP1(k) cnt += (e_##k >= mid) ? 1u : 0u;
    FOR11(CMP1)
#undef CMP1
    unsigned tot = (unsigned)__popcll(__ballot(cnt & 1u)) +
                   ((unsigned)__popcll(__ballot(cnt & 2u)) << 1) +
                   ((unsigned)__popcll(__ballot(cnt & 4u)) << 2) +
                   ((unsigned)__popcll(__ballot(cnt & 8u)) << 3);
    if (tot >= 11u) lo = mid; else hi = mid;
  }
  const unsigned E11 = lo;  // exact 11th-largest (encoded)

  // ---- 5. lane 0: combine per-wave whitelist partials, per-row loss ----
  if (lane == 0) {
#pragma unroll
    for (int j = 1; j < 4; ++j) {
      pmask |= sh_wpm[j];
#define CMB(l) lm_##l = fmaxf(lm_##l, sh_wlm[j][l]);
      FOR8(CMB)
#undef CMB
    }
    unsigned PR = pmask & 255u, PO = (pmask >> 8) & 255u;
    float thres = fmaxf(sigm(dec_u(E11)), 0.5f);
    float cmax = NEGF, imax = NEGF, umax = NEGF;
#define EP1(l)                                                   \
    if ((PR >> l) & 1u) {                                        \
      float ml = sigm(lm_##l);                                   \
      umax = fmaxf(umax, ml);                                    \
      if ((PO >> l) & 1u) cmax = fmaxf(cmax, ml);                \
      else imax = fmaxf(imax, ml);                               \
    }
    FOR8(EP1)
#undef EP1
    bool anyc = (PO != 0u);
    bool anyi = (PO != 255u);  // L == 8 labels always exist
    float x1 = anyc ? cmax : thres;
    float x2 = anyc ? (anyi ? fmaxf(imax, thres) : thres)
                    : ((nu > 0u) ? umax : NEGF);
    float coef = anyc ? 1.0f : 0.5f;
    float dd = x2 - x1 + 0.1f;
    float rank = ((dd > 0.0f) ? 2.0f : 1.0f) * sigm(10.0f * dd);
    partials[r] = coef * rank;
  }
}

__global__ void final_reduce(const float* __restrict__ partials,
                             float* __restrict__ out) {
  __shared__ float sh[4];
  const int tid = threadIdx.x;
  const int lane = tid & 63;
  const int wid = tid >> 6;
  float s = 0.0f;
  for (int i = tid; i < BB; i += 256) s += partials[i];
#pragma unroll
  for (int off = 32; off >= 1; off >>= 1) s += __shfl_xor(s, off, 64);
  if (lane == 0) sh[wid] = s;
  __syncthreads();
  if (tid == 0) out[0] = (sh[0] + sh[1] + sh[2] + sh[3]) * (1.0f / (float)BB);
}

extern "C" void kernel_launch(void* const* d_in, const int* in_sizes, int n_in,
                              void* d_out, int out_size, void* d_ws,
                              size_t ws_size, hipStream_t stream) {
  const float* x = (const float*)d_in[0];
  const float* y = (const float*)d_in[1];
  // d_in[2] (y_neg) is faithfully ignored — it never affects the loss.
  const unsigned char* wl = (const unsigned char*)d_in[3];
  float* out = (float*)d_out;
  unsigned* wsu = (unsigned*)d_ws;
  float* partials = (float*)((char*)d_ws + WS_PARTIALS_OFF);

  hipMemsetAsync(d_ws, 0, 16, stream);  // zero wsu[0..3]
  wl_sniff<<<64, 256, 0, stream>>>((const unsigned*)wl, wsu);
  wl_compact<<<(CC + 255) / 256, 256, 0, stream>>>(wl, wsu);
  loss_kernel<<<BB, 256, 0, stream>>>(x, y, wsu, partials);
  final_reduce<<<1, 256, 0, stream>>>(partials, out);
}